// Round 3
// baseline (524.783 us; speedup 1.0000x reference)
//
#include <hip/hip_runtime.h>

// 2-layer LSTM, B=4096, T=168, D=16, H1=64, H2=32, fp32 in/out.
// R3: same MFMA hi/lo-split structure as R2, but NB=8 batches/block with
// 512 blocks -> 2 blocks/CU (2 waves/SIMD) so the two blocks' barrier
// domains interleave and hide LDS/MFMA/transcendental latency.
// M=16 MFMA tile is half-used (rows 8..15 are garbage, never read back).

typedef __bf16 bf16x8 __attribute__((ext_vector_type(8)));
typedef float  f32x4  __attribute__((ext_vector_type(4)));

constexpr int T_SEQ = 168;
constexpr int DIN   = 16;
constexpr int NB    = 8;    // batch tile per block (M-tile rows 0..7 real)

__device__ __forceinline__ float fsig(float v)  { return __builtin_amdgcn_rcpf(1.f + __expf(-v)); }
__device__ __forceinline__ float ftanhf(float v){ return 2.f * __builtin_amdgcn_rcpf(1.f + __expf(-2.f * v)) - 1.f; }

__device__ __forceinline__ void split_bf16(float x, __bf16& hi, __bf16& lo) {
  hi = (__bf16)x;
  lo = (__bf16)(x - (float)hi);
}

__device__ __forceinline__ void load_frag8(const float* __restrict__ Wrow, int k0,
                                           bf16x8& hi, bf16x8& lo) {
#pragma unroll
  for (int j = 0; j < 8; ++j) {
    float v = Wrow[k0 + j];
    __bf16 h = (__bf16)v;
    hi[j] = h;
    lo[j] = (__bf16)(v - (float)h);
  }
}

#define MFMA(a, b, c) __builtin_amdgcn_mfma_f32_16x16x32_bf16((a), (b), (c), 0, 0, 0)

__global__ __launch_bounds__(256, 1)
void lstm_mfma_kernel(const float* __restrict__ x,
    const float* __restrict__ Wih1, const float* __restrict__ Whh1,
    const float* __restrict__ bih1, const float* __restrict__ bhh1,
    const float* __restrict__ Wih2, const float* __restrict__ Whh2,
    const float* __restrict__ bih2, const float* __restrict__ bhh2,
    const float* __restrict__ Wfc,  const float* __restrict__ bfc,
    float* __restrict__ out)
{
  // A-fragment tiles in exact lane order: [kb][lane][j] (j = 8 bf16 = 16B/lane)
  __shared__ __align__(16) __bf16 sA1[4 * 64 * 8];     // h1 hi(kb0,1)/lo(kb2,3)
  __shared__ __align__(16) __bf16 sA2[2 * 64 * 8];     // h2 hi(kb0)/lo(kb1)
  __shared__ __align__(16) __bf16 sAX[2 * 64 * 8];     // x: p0=[xh|xl], p1=[xl|xh]
  __shared__ __align__(16) __bf16 sB2[8 * 4 * 64 * 8]; // W_ih2 B-frags [nt][kb][lane][j]
  __shared__ __align__(16) float  sH2f[16 * 32];       // final-step h2 [batch][unit]

  const int tid  = threadIdx.x;
  const int w    = tid >> 6;        // wave 0..3
  const int lane = tid & 63;
  const int q    = lane >> 4;       // quad 0..3
  const int col  = lane & 15;
  const int b0   = blockIdx.x * NB;

  // ---------------- B-fragment (weight) setup: registers ----------------
  bf16x8 bhh[4][4];   // W_hh1, K=128 (hi kb0,1 | lo kb2,3)
  bf16x8 bih[4];      // W_ih1, K=32 packed [Wh(0..15); Wl(0..15)]
  float  b1v[4];
#pragma unroll
  for (int g = 0; g < 4; ++g) {
    const int r = g * 64 + w * 16 + col;
    const float* Wr = Whh1 + r * 64;
    bf16x8 h0, l0, h1f, l1f;
    load_frag8(Wr, 0 * 32 + q * 8, h0, l0);
    load_frag8(Wr, 1 * 32 + q * 8, h1f, l1f);
    bhh[g][0] = h0; bhh[g][1] = h1f; bhh[g][2] = l0; bhh[g][3] = l1f;
    const float* Wxr = Wih1 + r * 16;
    bf16x8 xh, xl;
    load_frag8(Wxr, (q & 1) * 8, xh, xl);
    bih[g] = (q < 2) ? xh : xl;   // k<16 -> hi, k>=16 -> lo
    b1v[g] = bih1[r] + bhh1[r];
  }
  bf16x8 bh2[4][2];   // W_hh2 (waves 0,1)
  float  b2v[4] = {0.f, 0.f, 0.f, 0.f};
  if (w < 2) {
#pragma unroll
    for (int g = 0; g < 4; ++g) {
      const int r = g * 32 + w * 16 + col;
      bf16x8 hh, ll;
      load_frag8(Whh2 + r * 32, q * 8, hh, ll);
      bh2[g][0] = hh; bh2[g][1] = ll;
      b2v[g] = bih2[r] + bhh2[r];
    }
  }

  // ---------------- LDS staging: W_ih2 B-frags ----------------
  for (int idx = tid; idx < 8 * 4 * 64; idx += 256) {
    const int nt = idx >> 8;
    const int kb = (idx >> 6) & 3;
    const int ln = idx & 63;
    const int qq = ln >> 4, cc = ln & 15;
    const int g  = nt >> 1, wv = nt & 1;
    const int r  = g * 32 + wv * 16 + cc;
    const int k0 = (kb & 1) * 32 + qq * 8;
    bf16x8 hh, ll;
    load_frag8(Wih2 + r * 64, k0, hh, ll);
    *(bf16x8*)&sB2[((nt * 4 + kb) * 64 + ln) * 8] = (kb < 2) ? hh : ll;
  }

  // ---------------- zero states + x tile, stage x(0) ----------------
  {
    bf16x8 z;
#pragma unroll
    for (int j = 0; j < 8; ++j) z[j] = (__bf16)0.f;
    for (int i = tid; i < 4 * 64; i += 256) *(bf16x8*)&sA1[i * 8] = z;
    for (int i = tid; i < 2 * 64; i += 256) *(bf16x8*)&sA2[i * 8] = z;
    for (int i = tid; i < 2 * 64; i += 256) *(bf16x8*)&sAX[i * 8] = z;
  }
  const int  bx   = tid >> 4, dx = tid & 15;
  const bool xldr = (tid < NB * DIN);   // 128 loader threads, one value each
  if (xldr) {
    float xv = x[(b0 + bx) * (T_SEQ * DIN) + 0 * DIN + dx];
    __bf16 xh, xl; split_bf16(xv, xh, xl);
    sAX[(0 * 64 + (dx >> 3) * 16 + bx) * 8 + (dx & 7)]       = xh;
    sAX[(0 * 64 + (2 + (dx >> 3)) * 16 + bx) * 8 + (dx & 7)] = xl;
    sAX[(1 * 64 + (dx >> 3) * 16 + bx) * 8 + (dx & 7)]       = xl;
    sAX[(1 * 64 + (2 + (dx >> 3)) * 16 + bx) * 8 + (dx & 7)] = xh;
  }
  __syncthreads();

  float c1s[4] = {0.f, 0.f, 0.f, 0.f};
  float c2s[4] = {0.f, 0.f, 0.f, 0.f};
  const int uu = w * 16 + col;

  for (int t = 0; t < T_SEQ; ++t) {
    // ======== Phase A: layer-1 gates (all 4 waves) ========
    bf16x8 a1[4], ax0, ax1;
#pragma unroll
    for (int kb = 0; kb < 4; ++kb) a1[kb] = *(const bf16x8*)&sA1[(kb * 64 + lane) * 8];
    ax0 = *(const bf16x8*)&sAX[(0 * 64 + lane) * 8];
    ax1 = *(const bf16x8*)&sAX[(1 * 64 + lane) * 8];

    float xpre = 0.f;
    if (xldr && t + 1 < T_SEQ) xpre = x[(b0 + bx) * (T_SEQ * DIN) + (t + 1) * DIN + dx];

    f32x4 c[4];
#pragma unroll
    for (int g = 0; g < 4; ++g) { c[g][0] = b1v[g]; c[g][1] = b1v[g]; c[g][2] = b1v[g]; c[g][3] = b1v[g]; }
#pragma unroll
    for (int g = 0; g < 4; ++g) {
      c[g] = MFMA(ax0, bih[g], c[g]);
      c[g] = MFMA(ax1, bih[g], c[g]);
#pragma unroll
      for (int kb = 0; kb < 4; ++kb) {
        c[g] = MFMA(a1[kb],     bhh[g][kb], c[g]);
        c[g] = MFMA(a1[kb ^ 2], bhh[g][kb], c[g]);
      }
    }
    __bf16 hhi[4], hlo[4];
#pragma unroll
    for (int r = 0; r < 4; ++r) {
      const float iv = fsig(c[0][r]);
      const float fv = fsig(c[1][r]);
      const float gv = ftanhf(c[2][r]);
      const float ov = fsig(c[3][r]);
      const float cc = fmaf(fv, c1s[r], iv * gv);
      c1s[r] = cc;
      split_bf16(ov * ftanhf(cc), hhi[r], hlo[r]);
    }
    __syncthreads();   // B0: all reads of sA1/sAX done

    { // write h1(t) in A-frag order
      const int kbh = uu >> 5;
      const int lnb = ((uu & 31) >> 3) * 16;
      const int jj  = uu & 7;
#pragma unroll
      for (int r = 0; r < 4; ++r) {
        const int m = q * 4 + r;
        sA1[((kbh * 64) + lnb + m) * 8 + jj]       = hhi[r];
        sA1[(((2 + kbh) * 64) + lnb + m) * 8 + jj] = hlo[r];
      }
    }
    if (xldr && t + 1 < T_SEQ) { // stage x(t+1)
      __bf16 xh, xl; split_bf16(xpre, xh, xl);
      sAX[(0 * 64 + (dx >> 3) * 16 + bx) * 8 + (dx & 7)]       = xh;
      sAX[(0 * 64 + (2 + (dx >> 3)) * 16 + bx) * 8 + (dx & 7)] = xl;
      sAX[(1 * 64 + (dx >> 3) * 16 + bx) * 8 + (dx & 7)]       = xl;
      sAX[(1 * 64 + (2 + (dx >> 3)) * 16 + bx) * 8 + (dx & 7)] = xh;
    }
    __syncthreads();   // B1: sA1 now holds h1(t)

    // ======== Phase B: layer-2 gates (waves 0,1) ========
    __bf16 h2hi[4], h2lo[4];
    float  h2f[4];
    if (w < 2) {
      bf16x8 a2[4], ah0, ah1;
#pragma unroll
      for (int kb = 0; kb < 4; ++kb) a2[kb] = *(const bf16x8*)&sA1[(kb * 64 + lane) * 8];
      ah0 = *(const bf16x8*)&sA2[(0 * 64 + lane) * 8];
      ah1 = *(const bf16x8*)&sA2[(1 * 64 + lane) * 8];

      f32x4 c2[4];
#pragma unroll
      for (int g = 0; g < 4; ++g) { c2[g][0] = b2v[g]; c2[g][1] = b2v[g]; c2[g][2] = b2v[g]; c2[g][3] = b2v[g]; }
#pragma unroll
      for (int g = 0; g < 4; ++g) {
        const int nt = g * 2 + w;
#pragma unroll
        for (int kb = 0; kb < 4; ++kb) {
          const bf16x8 bb = *(const bf16x8*)&sB2[((nt * 4 + kb) * 64 + lane) * 8];
          c2[g] = MFMA(a2[kb],     bb, c2[g]);
          c2[g] = MFMA(a2[kb ^ 2], bb, c2[g]);
        }
        c2[g] = MFMA(ah0, bh2[g][0], c2[g]);
        c2[g] = MFMA(ah1, bh2[g][1], c2[g]);
        c2[g] = MFMA(ah1, bh2[g][0], c2[g]);
        c2[g] = MFMA(ah0, bh2[g][1], c2[g]);
      }
#pragma unroll
      for (int r = 0; r < 4; ++r) {
        const float iv = fsig(c2[0][r]);
        const float fv = fsig(c2[1][r]);
        const float gv = ftanhf(c2[2][r]);
        const float ov = fsig(c2[3][r]);
        const float cc = fmaf(fv, c2s[r], iv * gv);
        c2s[r] = cc;
        h2f[r] = ov * ftanhf(cc);
        split_bf16(h2f[r], h2hi[r], h2lo[r]);
      }
    }
    __syncthreads();   // B2a: all reads of sA2/sA1 done

    if (w < 2) {
      const int lnb = ((uu & 31) >> 3) * 16;
      const int jj  = uu & 7;
#pragma unroll
      for (int r = 0; r < 4; ++r) {
        const int m = q * 4 + r;
        sA2[((0 * 64) + lnb + m) * 8 + jj] = h2hi[r];
        sA2[((1 * 64) + lnb + m) * 8 + jj] = h2lo[r];
        if (t == T_SEQ - 1) sH2f[m * 32 + uu] = h2f[r];
      }
    }
    __syncthreads();   // B2
  }

  // ======== FC epilogue ========
  if (tid < NB) {
    float s = bfc[0];
#pragma unroll
    for (int j = 0; j < 32; ++j) s = fmaf(Wfc[j], sH2f[tid * 32 + j], s);
    out[b0 + tid] = s;
  }
}

extern "C" void kernel_launch(void* const* d_in, const int* in_sizes, int n_in,
                              void* d_out, int out_size, void* d_ws, size_t ws_size,
                              hipStream_t stream) {
  (void)in_sizes; (void)n_in; (void)out_size; (void)d_ws; (void)ws_size;
  const float* x    = (const float*)d_in[0];
  const float* Wih1 = (const float*)d_in[1];
  const float* Whh1 = (const float*)d_in[2];
  const float* bih1 = (const float*)d_in[3];
  const float* bhh1 = (const float*)d_in[4];
  const float* Wih2 = (const float*)d_in[5];
  const float* Whh2 = (const float*)d_in[6];
  const float* bih2 = (const float*)d_in[7];
  const float* bhh2 = (const float*)d_in[8];
  const float* Wfc  = (const float*)d_in[9];
  const float* bfc  = (const float*)d_in[10];
  float* out = (float*)d_out;

  hipLaunchKernelGGL(lstm_mfma_kernel, dim3(4096 / NB), dim3(256), 0, stream,
                     x, Wih1, Whh1, bih1, bhh1, Wih2, Whh2, bih2, bhh2, Wfc, bfc, out);
}

// Round 4
// 300.162 us; speedup vs baseline: 1.7483x; 1.7483x over previous
//
#include <hip/hip_runtime.h>

// 2-layer LSTM, B=4096, T=168, D=16, H1=64, H2=32, fp32 in/out.
// R4: 512 threads/block (8 waves), NB=16, grid 256 (1 block/CU, 2 waves/SIMD).
// Wave specialization: waves 0-3 compute L1(t); waves 4-5 compute L2(t-1) in
// parallel (L2 needs only h1(t-1)); waves 6-7 prefetch x(t+1).
// Ping-pong LDS buffers (read buf[t&1], write buf[1-(t&1)]) -> ONE barrier
// per step (R2 had 4). No duplicated MFMA work (R3's mistake).
// Matmul: mfma_f32_16x16x32_bf16 with hi/lo bf16 split, fp32 accumulate.

typedef __bf16 bf16x8 __attribute__((ext_vector_type(8)));
typedef float  f32x4  __attribute__((ext_vector_type(4)));

constexpr int T_SEQ = 168;
constexpr int DIN   = 16;
constexpr int NB    = 16;

__device__ __forceinline__ float fsig(float v)  { return __builtin_amdgcn_rcpf(1.f + __expf(-v)); }
__device__ __forceinline__ float ftanhf(float v){ return 2.f * __builtin_amdgcn_rcpf(1.f + __expf(-2.f * v)) - 1.f; }

__device__ __forceinline__ void split_bf16(float x, __bf16& hi, __bf16& lo) {
  hi = (__bf16)x;
  lo = (__bf16)(x - (float)hi);
}

__device__ __forceinline__ void load_frag8(const float* __restrict__ Wrow, int k0,
                                           bf16x8& hi, bf16x8& lo) {
#pragma unroll
  for (int j = 0; j < 8; ++j) {
    float v = Wrow[k0 + j];
    __bf16 h = (__bf16)v;
    hi[j] = h;
    lo[j] = (__bf16)(v - (float)h);
  }
}

#define MFMA(a, b, c) __builtin_amdgcn_mfma_f32_16x16x32_bf16((a), (b), (c), 0, 0, 0)

__global__ __launch_bounds__(512, 1)
void lstm_mfma_kernel(const float* __restrict__ x,
    const float* __restrict__ Wih1, const float* __restrict__ Whh1,
    const float* __restrict__ bih1, const float* __restrict__ bhh1,
    const float* __restrict__ Wih2, const float* __restrict__ Whh2,
    const float* __restrict__ bih2, const float* __restrict__ bhh2,
    const float* __restrict__ Wfc,  const float* __restrict__ bfc,
    float* __restrict__ out)
{
  // A-fragment tiles in lane order [kb][lane][j], ping-pong buffered.
  __shared__ __align__(16) __bf16 sA1[2][4 * 64 * 8];   // h1 hi(kb0,1)/lo(kb2,3)
  __shared__ __align__(16) __bf16 sA2[2][2 * 64 * 8];   // h2 hi/lo
  __shared__ __align__(16) __bf16 sAX[2][2 * 64 * 8];   // x: p0=[xh|xl], p1=[xl|xh]
  __shared__ __align__(16) __bf16 sB2[8 * 4 * 64 * 8];  // W_ih2 B-frags [nt][kb][lane][j]
  __shared__ __align__(16) float  sH2f[16 * 32];        // final h2 [batch][unit]

  const int tid  = threadIdx.x;
  const int w    = tid >> 6;        // wave 0..7
  const int lane = tid & 63;
  const int q    = lane >> 4;
  const int col  = lane & 15;
  const int b0   = blockIdx.x * NB;

  const bool isL1 = (w < 4);
  const bool isL2 = (w == 4) || (w == 5);
  const bool isXL = (w >= 6);
  const int  wl   = w - 4;          // L2 wave index 0/1

  // ---------------- weights into registers ----------------
  bf16x8 bhh[4][4];   // W_hh1 (L1 waves)
  bf16x8 bih[4];      // W_ih1 packed [Wh;Wl]
  float  b1v[4] = {0.f, 0.f, 0.f, 0.f};
  if (isL1) {
#pragma unroll
    for (int g = 0; g < 4; ++g) {
      const int r = g * 64 + w * 16 + col;
      const float* Wr = Whh1 + r * 64;
      bf16x8 h0, l0, h1f, l1f;
      load_frag8(Wr, 0 * 32 + q * 8, h0, l0);
      load_frag8(Wr, 1 * 32 + q * 8, h1f, l1f);
      bhh[g][0] = h0; bhh[g][1] = h1f; bhh[g][2] = l0; bhh[g][3] = l1f;
      bf16x8 xh, xl;
      load_frag8(Wih1 + r * 16, (q & 1) * 8, xh, xl);
      bih[g] = (q < 2) ? xh : xl;
      b1v[g] = bih1[r] + bhh1[r];
    }
  }
  bf16x8 bh2[4][2];   // W_hh2 (L2 waves)
  float  b2v[4] = {0.f, 0.f, 0.f, 0.f};
  if (isL2) {
#pragma unroll
    for (int g = 0; g < 4; ++g) {
      const int r = g * 32 + wl * 16 + col;
      bf16x8 hh, ll;
      load_frag8(Whh2 + r * 32, q * 8, hh, ll);
      bh2[g][0] = hh; bh2[g][1] = ll;
      b2v[g] = bih2[r] + bhh2[r];
    }
  }

  // ---------------- LDS staging: W_ih2 B-frags ----------------
  for (int idx = tid; idx < 8 * 4 * 64; idx += 512) {
    const int nt = idx >> 8;
    const int kb = (idx >> 6) & 3;
    const int ln = idx & 63;
    const int qq = ln >> 4, cc = ln & 15;
    const int g  = nt >> 1, wv = nt & 1;
    const int r  = g * 32 + wv * 16 + cc;
    const int k0 = (kb & 1) * 32 + qq * 8;
    bf16x8 hh, ll;
    load_frag8(Wih2 + r * 64, k0, hh, ll);
    *(bf16x8*)&sB2[((nt * 4 + kb) * 64 + ln) * 8] = (kb < 2) ? hh : ll;
  }

  // ---------------- zero states, stage x(0) into buffer 0 ----------------
  {
    bf16x8 z;
#pragma unroll
    for (int j = 0; j < 8; ++j) z[j] = (__bf16)0.f;
    for (int i = tid; i < 2 * 4 * 64; i += 512) *(bf16x8*)&sA1[0][i * 8] = z;  // both bufs
    for (int i = tid; i < 2 * 2 * 64; i += 512) *(bf16x8*)&sA2[0][i * 8] = z;
    for (int i = tid; i < 2 * 2 * 64; i += 512) *(bf16x8*)&sAX[0][i * 8] = z;
  }
  // x loader mapping (waves 6,7): 128 threads x 2 values (float2)
  const int xi = tid - 384;
  const int bx = (xi >> 3) & 15;
  const int d2 = (xi & 7) * 2;
  if (isXL) {
    const float2 xv = *(const float2*)&x[((size_t)(b0 + bx) * T_SEQ + 0) * DIN + d2];
    const float vv[2] = {xv.x, xv.y};
#pragma unroll
    for (int s = 0; s < 2; ++s) {
      const int d = d2 + s;
      __bf16 xh, xl; split_bf16(vv[s], xh, xl);
      sAX[0][(0 * 64 + (d >> 3) * 16 + bx) * 8 + (d & 7)]       = xh;
      sAX[0][(0 * 64 + (2 + (d >> 3)) * 16 + bx) * 8 + (d & 7)] = xl;
      sAX[0][(1 * 64 + (d >> 3) * 16 + bx) * 8 + (d & 7)]       = xl;
      sAX[0][(1 * 64 + (2 + (d >> 3)) * 16 + bx) * 8 + (d & 7)] = xh;
    }
  }
  __syncthreads();

  float c1s[4] = {0.f, 0.f, 0.f, 0.f};
  float c2s[4] = {0.f, 0.f, 0.f, 0.f};
  const int uu  = w * 16 + col;     // L1 unit (w<4)
  const int uu2 = wl * 16 + col;    // L2 unit (w==4,5)

  // t = 0..T_SEQ inclusive: L1 computes h1(t) for t<T, L2 computes h2(t-1) for t>=1.
  for (int t = 0; t <= T_SEQ; ++t) {
    const int p = t & 1;

    if (isL1 && t < T_SEQ) {
      bf16x8 a1[4], ax0, ax1;
#pragma unroll
      for (int kb = 0; kb < 4; ++kb) a1[kb] = *(const bf16x8*)&sA1[p][(kb * 64 + lane) * 8];
      ax0 = *(const bf16x8*)&sAX[p][(0 * 64 + lane) * 8];
      ax1 = *(const bf16x8*)&sAX[p][(1 * 64 + lane) * 8];

      f32x4 c[4];
#pragma unroll
      for (int g = 0; g < 4; ++g) { c[g][0] = b1v[g]; c[g][1] = b1v[g]; c[g][2] = b1v[g]; c[g][3] = b1v[g]; }
#pragma unroll
      for (int g = 0; g < 4; ++g) {
        c[g] = MFMA(ax0, bih[g], c[g]);
        c[g] = MFMA(ax1, bih[g], c[g]);
#pragma unroll
        for (int kb = 0; kb < 4; ++kb) {
          c[g] = MFMA(a1[kb],     bhh[g][kb], c[g]);
          c[g] = MFMA(a1[kb ^ 2], bhh[g][kb], c[g]);
        }
      }
      const int kbh = uu >> 5;
      const int lnb = ((uu & 31) >> 3) * 16;
      const int jj  = uu & 7;
#pragma unroll
      for (int r = 0; r < 4; ++r) {
        const float iv = fsig(c[0][r]);
        const float fv = fsig(c[1][r]);
        const float gv = ftanhf(c[2][r]);
        const float ov = fsig(c[3][r]);
        const float cc = fmaf(fv, c1s[r], iv * gv);
        c1s[r] = cc;
        __bf16 hh, hl;
        split_bf16(ov * ftanhf(cc), hh, hl);
        const int m = q * 4 + r;
        sA1[1 - p][((kbh * 64) + lnb + m) * 8 + jj]       = hh;
        sA1[1 - p][(((2 + kbh) * 64) + lnb + m) * 8 + jj] = hl;
      }
    }

    if (isL2 && t >= 1) {
      bf16x8 a2[4], ah0, ah1;
#pragma unroll
      for (int kb = 0; kb < 4; ++kb) a2[kb] = *(const bf16x8*)&sA1[p][(kb * 64 + lane) * 8];
      ah0 = *(const bf16x8*)&sA2[p][(0 * 64 + lane) * 8];
      ah1 = *(const bf16x8*)&sA2[p][(1 * 64 + lane) * 8];

      f32x4 c2[4];
#pragma unroll
      for (int g = 0; g < 4; ++g) { c2[g][0] = b2v[g]; c2[g][1] = b2v[g]; c2[g][2] = b2v[g]; c2[g][3] = b2v[g]; }
#pragma unroll
      for (int g = 0; g < 4; ++g) {
        const int nt = g * 2 + wl;
#pragma unroll
        for (int kb = 0; kb < 4; ++kb) {
          const bf16x8 bb = *(const bf16x8*)&sB2[((nt * 4 + kb) * 64 + lane) * 8];
          c2[g] = MFMA(a2[kb],     bb, c2[g]);
          c2[g] = MFMA(a2[kb ^ 2], bb, c2[g]);
        }
        c2[g] = MFMA(ah0, bh2[g][0], c2[g]);
        c2[g] = MFMA(ah1, bh2[g][1], c2[g]);
        c2[g] = MFMA(ah1, bh2[g][0], c2[g]);
        c2[g] = MFMA(ah0, bh2[g][1], c2[g]);
      }
      const int lnb2 = ((uu2 & 31) >> 3) * 16;
      const int jj2  = uu2 & 7;
#pragma unroll
      for (int r = 0; r < 4; ++r) {
        const float iv = fsig(c2[0][r]);
        const float fv = fsig(c2[1][r]);
        const float gv = ftanhf(c2[2][r]);
        const float ov = fsig(c2[3][r]);
        const float cc = fmaf(fv, c2s[r], iv * gv);
        c2s[r] = cc;
        const float hf = ov * ftanhf(cc);
        __bf16 hh, hl;
        split_bf16(hf, hh, hl);
        const int m = q * 4 + r;
        sA2[1 - p][((0 * 64) + lnb2 + m) * 8 + jj2] = hh;
        sA2[1 - p][((1 * 64) + lnb2 + m) * 8 + jj2] = hl;
        if (t == T_SEQ) sH2f[m * 32 + uu2] = hf;
      }
    }

    if (isXL && t + 1 < T_SEQ) {
      const float2 xv = *(const float2*)&x[((size_t)(b0 + bx) * T_SEQ + (t + 1)) * DIN + d2];
      const float vv[2] = {xv.x, xv.y};
#pragma unroll
      for (int s = 0; s < 2; ++s) {
        const int d = d2 + s;
        __bf16 xh, xl; split_bf16(vv[s], xh, xl);
        sAX[1 - p][(0 * 64 + (d >> 3) * 16 + bx) * 8 + (d & 7)]       = xh;
        sAX[1 - p][(0 * 64 + (2 + (d >> 3)) * 16 + bx) * 8 + (d & 7)] = xl;
        sAX[1 - p][(1 * 64 + (d >> 3) * 16 + bx) * 8 + (d & 7)]       = xl;
        sAX[1 - p][(1 * 64 + (2 + (d >> 3)) * 16 + bx) * 8 + (d & 7)] = xh;
      }
    }

    __syncthreads();   // single barrier: separates step-t reads from step-t+1 writes
  }

  // ======== FC epilogue ========
  if (tid < NB) {
    float s = bfc[0];
#pragma unroll
    for (int j = 0; j < 32; ++j) s = fmaf(Wfc[j], sH2f[tid * 32 + j], s);
    out[b0 + tid] = s;
  }
}

extern "C" void kernel_launch(void* const* d_in, const int* in_sizes, int n_in,
                              void* d_out, int out_size, void* d_ws, size_t ws_size,
                              hipStream_t stream) {
  (void)in_sizes; (void)n_in; (void)out_size; (void)d_ws; (void)ws_size;
  const float* x    = (const float*)d_in[0];
  const float* Wih1 = (const float*)d_in[1];
  const float* Whh1 = (const float*)d_in[2];
  const float* bih1 = (const float*)d_in[3];
  const float* bhh1 = (const float*)d_in[4];
  const float* Wih2 = (const float*)d_in[5];
  const float* Whh2 = (const float*)d_in[6];
  const float* bih2 = (const float*)d_in[7];
  const float* bhh2 = (const float*)d_in[8];
  const float* Wfc  = (const float*)d_in[9];
  const float* bfc  = (const float*)d_in[10];
  float* out = (float*)d_out;

  hipLaunchKernelGGL(lstm_mfma_kernel, dim3(4096 / NB), dim3(512), 0, stream,
                     x, Wih1, Whh1, bih1, bhh1, Wih2, Whh2, bih2, bhh2, Wfc, bfc, out);
}